// Round 7
// baseline (2932.231 us; speedup 1.0000x reference)
//
#include <hip/hip_runtime.h>
#include <math.h>

// MultiRNNCell: 2-layer LSTM-imputation scan. B=64, T=128, D=256, H=1024.
// R6: ring-buffered dataflow. Every cross-block tensor (h, h0, imputed) and
// every flag set gets a FRESH address per timestep (no reuse within a launch):
//  - producers: sc0 sc1 write-through stores -> MALL (non-coherent L2 never
//    holds dirty copies), per-wave vmcnt(0), relaxed agent flag store (==1)
//  - consumers: PLAIN CACHED vectorized loads. Fresh addresses => compulsory
//    miss => L2 fill from MALL shared by all 32 CUs of the XCD. No buffer_inv,
//    no sc1 reads, no fences. This converts the former latency-bound uncached
//    pull (~4-6 B/cyc/CU) into shared cached bandwidth.
//  - flags polled sc1 (always fresh from MALL); poison 0xAA != 1 => no init.
//  - all prep in-kernel (fp32->bf16 weight frags into LDS, bias folds,
//    h(-1)=0 written by l1 blocks) => single dispatch.
// 144 blocks x 256 thr, 120KB LDS -> 1 block/CU, all co-resident.
// Dead forget gate removed; layer1 weight fold W1 = Wih1+Whh1.

#define B_ 64
#define T_ 128
#define D_ 256
#define H_ 1024

#define NL0 64
#define NL1 64
#define NEST 16
#define NBLK (NL0 + NL1 + NEST)   // 144

#define KS0 40          // layer0 ksteps: 8 (imputed, D=256) + 32 (h, H=1024)
#define KS1 32          // layer1 ksteps (H=1024)
#define KSE 32          // est ksteps (H=1024)

#define RS_H   ((size_t)B_ * H_)   // 65536 bf16 = 128 KB per slot
#define RS_IMP ((size_t)B_ * D_)   // 16384 bf16 = 32 KB per slot

typedef __attribute__((ext_vector_type(8))) short short8;   // 8 bf16
typedef __attribute__((ext_vector_type(4))) float floatx4;  // MFMA C/D

__device__ __forceinline__ unsigned short f2bf(float x) {
    union { float f; unsigned u; } v; v.f = x;
    unsigned r = v.u + 0x7fffu + ((v.u >> 16) & 1u);  // RNE
    return (unsigned short)(r >> 16);
}
__device__ __forceinline__ float sigmoidf_(float x) { return 1.0f / (1.0f + expf(-x)); }

// write-through 2B store to the MALL coherence point (bypasses L1+L2)
__device__ __forceinline__ void st_short_sc(unsigned short* p, unsigned v) {
    asm volatile("global_store_short %0, %1, off sc0 sc1"
                 :: "v"(p), "v"(v) : "memory");
}
__device__ __forceinline__ void vm_drain() {
    asm volatile("s_waitcnt vmcnt(0)" ::: "memory");
}

// Wait until this step's flag row flags[0..P) all == 1 (ring: one row per
// step, never reused; 0xAA poison never compares equal). sc1 relaxed polls
// are always served from MALL -> fresh, no fences needed anywhere.
__device__ __forceinline__ void wait_ready(const int* flags, int P) {
    if ((int)threadIdx.x < P) {
        while (__hip_atomic_load(flags + threadIdx.x, __ATOMIC_RELAXED,
                                 __HIP_MEMORY_SCOPE_AGENT) != 1) {}
    }
    __syncthreads();
}
// Producer data already at MALL (sc1 stores + per-wave vmcnt drain before the
// barrier). Flag store relaxed agent (sc1 write-through). No release fence.
__device__ __forceinline__ void signal_flag(int* flag) {
    __syncthreads();
    if (threadIdx.x == 0)
        __hip_atomic_store(flag, 1, __ATOMIC_RELAXED, __HIP_MEMORY_SCOPE_AGENT);
}

// ---------------- fused persistent kernel (single dispatch) ----------------
__global__ __launch_bounds__(256, 1) void k_fused(
    const float* __restrict__ Wih0, const float* __restrict__ Whh0,
    const float* __restrict__ bih0, const float* __restrict__ bhh0,
    const float* __restrict__ Wih1, const float* __restrict__ Whh1,
    const float* __restrict__ bih1, const float* __restrict__ bhh1,
    const float* __restrict__ Wout, const float* __restrict__ bout,
    const float* __restrict__ X, const float* __restrict__ Mm,
    unsigned short* __restrict__ hR,    // (T_+1) slots
    unsigned short* __restrict__ h0R,   // T_ slots
    unsigned short* __restrict__ impR,  // T_ slots
    int* __restrict__ fL1,              // (T_+1) x 64
    int* __restrict__ fL0,              // T_ x 64
    int* __restrict__ fE,               // T_ x 16
    float* __restrict__ out)
{
    // weight fragments: [fragIdx][lane][8 bf16]; ds_read_b128 conflict-free
    __shared__ unsigned short ldsW[3 * KS0 * 64 * 8];   // 120 KB (l0 blocks)

    const int tid  = threadIdx.x;
    const int lane = tid & 63;
    const int wv   = tid >> 6;       // wave id = m-tile (16 batch rows)
    const int r16  = lane & 15, q = lane >> 4;
    const int bx   = blockIdx.x;
    const int m0   = wv * 16;
    const unsigned short* lfrag = ldsW + lane * 8;   // + fragIdx*512

    // ---- one-time: convert fp32 weights into LDS fragment order (bf16) ----
    if (bx < NL0) {
        int n0 = bx * 16;
        for (int idx = wv; idx < 3 * KS0; idx += 4) {
            int gi = idx / KS0, k = idx % KS0;
            int grow = (gi == 0) ? 0 : (gi == 1 ? 2 * H_ : 3 * H_);
            int row = grow + n0 + r16;
            const float* src = (k < 8) ? (Wih0 + (size_t)row * D_ + k * 32 + q * 8)
                                       : (Whh0 + (size_t)row * H_ + (k - 8) * 32 + q * 8);
            short8 w;
            #pragma unroll
            for (int j = 0; j < 8; ++j) w[j] = (short)f2bf(src[j]);
            *(short8*)(ldsW + ((size_t)idx * 64 + lane) * 8) = w;
        }
    } else if (bx < NL0 + NL1) {
        int n0 = (bx - NL0) * 16;
        for (int idx = wv; idx < 3 * KS1; idx += 4) {
            int gi = idx / KS1, k = idx % KS1;
            int grow = (gi == 0) ? 0 : (gi == 1 ? 2 * H_ : 3 * H_);
            size_t off = (size_t)(grow + n0 + r16) * H_ + k * 32 + q * 8;
            short8 w;
            #pragma unroll
            for (int j = 0; j < 8; ++j) w[j] = (short)f2bf(Wih1[off + j] + Whh1[off + j]);
            *(short8*)(ldsW + ((size_t)idx * 64 + lane) * 8) = w;
        }
    } else {
        int d0 = (bx - NL0 - NL1) * 16;
        for (int idx = wv; idx < KSE; idx += 4) {
            const float* src = Wout + (size_t)(d0 + r16) * H_ + idx * 32 + q * 8;
            short8 w;
            #pragma unroll
            for (int j = 0; j < 8; ++j) w[j] = (short)f2bf(src[j]);
            *(short8*)(ldsW + ((size_t)idx * 64 + lane) * 8) = w;
        }
    }
    __syncthreads();

    if (bx < NL0) {
        // =============== layer-0 blocks ===============
        const int n = bx * 16 + r16;
        const float bi = bih0[n] + bhh0[n];
        const float bg = bih0[2 * H_ + n] + bhh0[2 * H_ + n];
        const float bo = bih0[3 * H_ + n] + bhh0[3 * H_ + n];
        for (int t = 0; t < T_; ++t) {
            wait_ready(fL1 + (size_t)t * 64, 64);     // h(t-1) = slot t ready
            floatx4 ai = {0.f,0.f,0.f,0.f}, ag = ai, ao = ai;
            {   // h-part (overlaps est blocks' work); plain cached loads
                const unsigned short* aB = hR + (size_t)t * RS_H + (m0 + r16) * H_ + q * 8;
                #pragma unroll 4
                for (int k = 0; k < 32; ++k) {
                    short8 a = *(const short8*)(aB + k * 32);
                    ai = __builtin_amdgcn_mfma_f32_16x16x32_bf16(a, *(const short8*)(lfrag + (0*KS0 + k + 8)*512), ai, 0,0,0);
                    ag = __builtin_amdgcn_mfma_f32_16x16x32_bf16(a, *(const short8*)(lfrag + (1*KS0 + k + 8)*512), ag, 0,0,0);
                    ao = __builtin_amdgcn_mfma_f32_16x16x32_bf16(a, *(const short8*)(lfrag + (2*KS0 + k + 8)*512), ao, 0,0,0);
                }
            }
            wait_ready(fE + (size_t)t * 16, 16);      // imputed(t) ready
            {   // imputed part + activation
                const unsigned short* aB = impR + (size_t)t * RS_IMP + (m0 + r16) * D_ + q * 8;
                #pragma unroll
                for (int k = 0; k < 8; ++k) {
                    short8 a = *(const short8*)(aB + k * 32);
                    ai = __builtin_amdgcn_mfma_f32_16x16x32_bf16(a, *(const short8*)(lfrag + (0*KS0 + k)*512), ai, 0,0,0);
                    ag = __builtin_amdgcn_mfma_f32_16x16x32_bf16(a, *(const short8*)(lfrag + (1*KS0 + k)*512), ag, 0,0,0);
                    ao = __builtin_amdgcn_mfma_f32_16x16x32_bf16(a, *(const short8*)(lfrag + (2*KS0 + k)*512), ao, 0,0,0);
                }
                unsigned short* h0S = h0R + (size_t)t * RS_H;
                #pragma unroll
                for (int r = 0; r < 4; r++) {
                    int bb = m0 + q * 4 + r;
                    float c = sigmoidf_(ai[r] + bi) * tanhf(ag[r] + bg);
                    float h = sigmoidf_(ao[r] + bo) * tanhf(c);
                    st_short_sc(&h0S[bb * H_ + n], (unsigned)f2bf(h));
                }
            }
            vm_drain();
            signal_flag(fL0 + (size_t)t * 64 + bx);
        }
    } else if (bx < NL0 + NL1) {
        // =============== layer-1 blocks ===============
        const int j = bx - NL0;
        const int n = j * 16 + r16;
        const float bi = bih1[n] + bhh1[n];
        const float bg = bih1[2 * H_ + n] + bhh1[2 * H_ + n];
        const float bo = bih1[3 * H_ + n] + bhh1[3 * H_ + n];
        // h(-1) = 0 -> write zeros into hR slot 0, then flag it
        #pragma unroll
        for (int r = 0; r < 4; r++)
            st_short_sc(&hR[(size_t)(m0 + q * 4 + r) * H_ + n], 0);
        vm_drain();
        signal_flag(fL1 + j);
        for (int t = 0; t < T_; ++t) {
            wait_ready(fL0 + (size_t)t * 64, 64);     // h0(t) ready
            floatx4 li = {0.f,0.f,0.f,0.f}, lg = li, lo = li;
            const unsigned short* aB = h0R + (size_t)t * RS_H + (m0 + r16) * H_ + q * 8;
            #pragma unroll 4
            for (int k = 0; k < KS1; ++k) {
                short8 a = *(const short8*)(aB + k * 32);
                li = __builtin_amdgcn_mfma_f32_16x16x32_bf16(a, *(const short8*)(lfrag + (0*KS1 + k)*512), li, 0,0,0);
                lg = __builtin_amdgcn_mfma_f32_16x16x32_bf16(a, *(const short8*)(lfrag + (1*KS1 + k)*512), lg, 0,0,0);
                lo = __builtin_amdgcn_mfma_f32_16x16x32_bf16(a, *(const short8*)(lfrag + (2*KS1 + k)*512), lo, 0,0,0);
            }
            float hv[4];
            unsigned short* hS = hR + (size_t)(t + 1) * RS_H;
            #pragma unroll
            for (int r = 0; r < 4; r++) {
                int bb = m0 + q * 4 + r;
                float c = sigmoidf_(li[r] + bi) * tanhf(lg[r] + bg);
                hv[r] = sigmoidf_(lo[r] + bo) * tanhf(c);
                st_short_sc(&hS[bb * H_ + n], (unsigned)f2bf(hv[r]));
            }
            vm_drain();
            signal_flag(fL1 + (size_t)(t + 1) * 64 + j);
            if (t == T_ - 1) {
                #pragma unroll
                for (int r = 0; r < 4; r++)
                    out[(size_t)B_ * T_ * D_ + (size_t)(m0 + q * 4 + r) * H_ + n] = hv[r];
            }
        }
    } else {
        // =============== est/impute blocks ===============
        const int e  = bx - NL0 - NL1;
        const int dd = e * 16 + r16;
        const float bo_ = bout[dd];
        for (int t = 0; t < T_; ++t) {
            // prefetch X/Mm for this step BEFORE waiting (read-only, cached)
            float xv[4], mv[4];
            #pragma unroll
            for (int r = 0; r < 4; r++) {
                int bb = m0 + q * 4 + r;
                xv[r] = X [(size_t)(bb * T_ + t) * D_ + dd];
                mv[r] = Mm[(size_t)(bb * T_ + t) * D_ + dd];
            }
            asm volatile("" ::: "memory");            // pin prefetch before wait
            wait_ready(fL1 + (size_t)t * 64, 64);     // h(t-1) = slot t ready
            floatx4 a0 = {0.f,0.f,0.f,0.f}, a1 = a0;  // 2-way acc chain split
            const unsigned short* aB = hR + (size_t)t * RS_H + (m0 + r16) * H_ + q * 8;
            #pragma unroll 4
            for (int k = 0; k < 16; ++k) {
                short8 x0 = *(const short8*)(aB + (2*k  ) * 32);
                short8 x1 = *(const short8*)(aB + (2*k+1) * 32);
                a0 = __builtin_amdgcn_mfma_f32_16x16x32_bf16(x0, *(const short8*)(lfrag + (2*k  )*512), a0, 0,0,0);
                a1 = __builtin_amdgcn_mfma_f32_16x16x32_bf16(x1, *(const short8*)(lfrag + (2*k+1)*512), a1, 0,0,0);
            }
            float estv[4];
            unsigned short* iS = impR + (size_t)t * RS_IMP;
            #pragma unroll
            for (int r = 0; r < 4; r++) {
                int bb = m0 + q * 4 + r;
                estv[r] = a0[r] + a1[r] + bo_;
                st_short_sc(&iS[bb * D_ + dd],
                            (unsigned)f2bf(mv[r] * xv[r] + (1.0f - mv[r]) * estv[r]));
            }
            vm_drain();
            signal_flag(fE + (size_t)t * 16 + e);
            if (t >= 1) {
                #pragma unroll
                for (int r = 0; r < 4; r++) {
                    int bb = m0 + q * 4 + r;
                    out[(size_t)(bb * T_ + (t - 1)) * D_ + dd] = estv[r];
                }
            }
        }
        // final projection: est from h(T-1) (= slot T_) -> out[:, T-1, :]
        wait_ready(fL1 + (size_t)T_ * 64, 64);
        floatx4 a0 = {0.f,0.f,0.f,0.f}, a1 = a0;
        const unsigned short* aB = hR + (size_t)T_ * RS_H + (m0 + r16) * H_ + q * 8;
        #pragma unroll 4
        for (int k = 0; k < 16; ++k) {
            short8 x0 = *(const short8*)(aB + (2*k  ) * 32);
            short8 x1 = *(const short8*)(aB + (2*k+1) * 32);
            a0 = __builtin_amdgcn_mfma_f32_16x16x32_bf16(x0, *(const short8*)(lfrag + (2*k  )*512), a0, 0,0,0);
            a1 = __builtin_amdgcn_mfma_f32_16x16x32_bf16(x1, *(const short8*)(lfrag + (2*k+1)*512), a1, 0,0,0);
        }
        #pragma unroll
        for (int r = 0; r < 4; r++) {
            int bb = m0 + q * 4 + r;
            out[(size_t)(bb * T_ + (T_ - 1)) * D_ + dd] = a0[r] + a1[r] + bo_;
        }
    }
}

extern "C" void kernel_launch(void* const* d_in, const int* in_sizes, int n_in,
                              void* d_out, int out_size, void* d_ws, size_t ws_size,
                              hipStream_t stream) {
    const float* X    = (const float*)d_in[0];
    const float* Mm   = (const float*)d_in[1];
    const float* Wih0 = (const float*)d_in[2];
    const float* Whh0 = (const float*)d_in[3];
    const float* bih0 = (const float*)d_in[4];
    const float* bhh0 = (const float*)d_in[5];
    const float* Wih1 = (const float*)d_in[6];
    const float* Whh1 = (const float*)d_in[7];
    const float* bih1 = (const float*)d_in[8];
    const float* bhh1 = (const float*)d_in[9];
    const float* Wout = (const float*)d_in[10];
    const float* bout = (const float*)d_in[11];
    float* out = (float*)d_out;

    // ring workspace carve-up (256B aligned); no initialization required:
    // flags use ==1 vs 0xAA poison, hR slot 0 zeroed in-kernel by l1 blocks.
    char* ws = (char*)d_ws;
    size_t off = 0;
    auto alloc = [&](size_t bytes) { char* p = ws + off; off = (off + bytes + 255) & ~(size_t)255; return p; };
    unsigned short* hR   = (unsigned short*)alloc((size_t)(T_ + 1) * RS_H * 2);   // 16.5 MB
    unsigned short* h0R  = (unsigned short*)alloc((size_t)T_ * RS_H * 2);         // 16.0 MB
    unsigned short* impR = (unsigned short*)alloc((size_t)T_ * RS_IMP * 2);       //  4.0 MB
    int*            fL1  = (int*)alloc((size_t)(T_ + 1) * 64 * 4);
    int*            fL0  = (int*)alloc((size_t)T_ * 64 * 4);
    int*            fE   = (int*)alloc((size_t)T_ * 16 * 4);

    k_fused<<<NBLK, 256, 0, stream>>>(Wih0, Whh0, bih0, bhh0, Wih1, Whh1, bih1, bhh1,
                                      Wout, bout, X, Mm,
                                      hR, h0R, impR, fL1, fL0, fE, out);
}